// Round 6
// baseline (3496.635 us; speedup 1.0000x reference)
//
#include <hip/hip_runtime.h>

#define SQ   2048
#define HIDN 1024
#define NB   4
#define NH   16
#define HD   64

typedef __attribute__((ext_vector_type(4))) float f32x4;

__device__ __forceinline__ short f2bf(float f) {
  union { float f; unsigned u; } x; x.f = f;
  unsigned r = (x.u + 0x7fffu + ((x.u >> 16) & 1u)) >> 16;
  return (short)r;
}
__device__ __forceinline__ float bf2f(int s) {
  union { unsigned u; float f; } x;
  x.u = ((unsigned)(unsigned short)s) << 16;
  return x.f;
}

// ---------------------------------------------------------------------------
// K0: normalize mask to fp32 (auto-detect int32 / byte-bool / fp32).
// ---------------------------------------------------------------------------
__global__ __launch_bounds__(256) void k_maskprep(const unsigned* __restrict__ mraw,
                                                  float* __restrict__ m) {
  __shared__ unsigned red[256];
  const int tid = threadIdx.x;
  unsigned w_or = 0;
  for (int i = tid; i < 2048; i += 256) w_or |= mraw[i];   // first 8192 bytes
  red[tid] = w_or;
  __syncthreads();
  for (int s = 128; s > 0; s >>= 1) {
    if (tid < s) red[tid] |= red[tid + s];
    __syncthreads();
  }
  const unsigned allw = red[0];
  int mode;                                      // 0=int32, 1=uint8, 2=fp32
  if ((allw & 0xFFFFFFFEu) == 0) mode = 0;
  else if ((allw & 0xFEFEFEFEu) == 0) mode = 1;
  else mode = 2;
  const unsigned char* mb = (const unsigned char*)mraw;
  const float* mf = (const float*)mraw;
  const int* mi = (const int*)mraw;
  for (int i = tid; i < NB * SQ; i += 256) {
    float v;
    if (mode == 0)      v = mi[i] ? 1.0f : 0.0f;
    else if (mode == 1) v = mb[i] ? 1.0f : 0.0f;
    else                v = (mf[i] != 0.0f) ? 1.0f : 0.0f;
    m[i] = v;
  }
}

// ---------------------------------------------------------------------------
// K1: QKV projections, fp32 VALU GEMM. C[r,c] = A[r,:]·W[c,:] + bias[c].
// z=0: q*0.125 -> qh; z=1: k -> kh; z=2: v -> vh. All [b,h,s,d] bf16 in ws.
// ---------------------------------------------------------------------------
__global__ __launch_bounds__(256) void k_gemm_qkv(
    const float* __restrict__ query,
    const float* __restrict__ Wq, const float* __restrict__ bq,
    const float* __restrict__ Wk, const float* __restrict__ bk,
    const float* __restrict__ Wv, const float* __restrict__ bv,
    short* __restrict__ qh, short* __restrict__ kh, short* __restrict__ vh)
{
  __shared__ float As[64][17];
  __shared__ float Bs[64][17];
  const int z = blockIdx.z;
  const float* __restrict__ W    = (z == 0) ? Wq : (z == 1) ? Wk : Wv;
  const float* __restrict__ bias = (z == 0) ? bq : (z == 1) ? bk : bv;
  const int row0 = blockIdx.y * 64, col0 = blockIdx.x * 64;
  const int tid = threadIdx.x;
  const int tx = tid & 15, ty = tid >> 4;
  float acc[4][4] = {};
  for (int k0 = 0; k0 < HIDN; k0 += 16) {
#pragma unroll
    for (int p = 0; p < 4; ++p) {
      const int el = tid + p * 256;
      const int r = el >> 4, kk = el & 15;
      As[r][kk] = query[(row0 + r) * HIDN + k0 + kk];
      Bs[r][kk] = W[(col0 + r) * HIDN + k0 + kk];
    }
    __syncthreads();
#pragma unroll
    for (int e = 0; e < 16; ++e) {
      float a[4], b[4];
#pragma unroll
      for (int i = 0; i < 4; ++i) a[i] = As[ty + 16 * i][e];
#pragma unroll
      for (int j = 0; j < 4; ++j) b[j] = Bs[tx + 16 * j][e];
#pragma unroll
      for (int i = 0; i < 4; ++i)
#pragma unroll
        for (int j = 0; j < 4; ++j) acc[i][j] = fmaf(a[i], b[j], acc[i][j]);
    }
    __syncthreads();
  }
#pragma unroll
  for (int i = 0; i < 4; ++i)
#pragma unroll
    for (int j = 0; j < 4; ++j) {
      const int row = row0 + ty + 16 * i;       // [0, 8192)
      const int col = col0 + tx + 16 * j;       // [0, 1024)
      const float v = acc[i][j] + bias[col];
      const int b = row >> 11, s = row & (SQ - 1);
      const int h = col >> 6, d = col & (HD - 1);
      const int idx = ((b * NH + h) * SQ + s) * HD + d;
      if (z == 0)      qh[idx] = f2bf(v * 0.125f);
      else if (z == 1) kh[idx] = f2bf(v);
      else             vh[idx] = f2bf(v);
    }
}

// ---------------------------------------------------------------------------
// K2: per-column (query-axis) softmax denominators.
// Lnv[j] = 1 / sum_i exp((q_i·k_j)*mi*mj).  |E|<=~4, no max-shift needed.
// Thread owns column j: k_j in 64 VGPRs, q rows streamed (wave-uniform loads).
// ---------------------------------------------------------------------------
__global__ __launch_bounds__(256) void k_sumexp(
    const short* __restrict__ qh, const short* __restrict__ kh,
    const float* __restrict__ mfl, float* __restrict__ Lnv)
{
  const int bh = blockIdx.y, b = bh >> 4;
  const int j = blockIdx.x * 256 + threadIdx.x;
  float kreg[HD];
#pragma unroll
  for (int d = 0; d < HD; ++d) kreg[d] = bf2f(kh[(bh * SQ + j) * HD + d]);
  const float mj = mfl[b * SQ + j];
  const unsigned* qbase = (const unsigned*)qh + bh * SQ * (HD / 2);
  float L = 0.f;
  for (int i = 0; i < SQ; ++i) {
    const unsigned* qr = qbase + i * (HD / 2);   // uniform across threads
    float dot = 0.f;
#pragma unroll
    for (int t = 0; t < HD / 2; ++t) {
      const unsigned u = qr[t];
      const float qlo = __uint_as_float(u << 16);
      const float qhi = __uint_as_float(u & 0xFFFF0000u);
      dot = fmaf(qlo, kreg[2 * t], dot);
      dot = fmaf(qhi, kreg[2 * t + 1], dot);
    }
    const float mi = mfl[b * SQ + i];
    L += __expf(dot * (mi * mj));
  }
  Lnv[bh * SQ + j] = 1.0f / L;
}

// ---------------------------------------------------------------------------
// K3: x[i,d] = sum_j exp(E[i,j]*mi*mj) * Lnv[j] * v[j,d]   (faithful axis=2).
// Block: one (bh, 64-row i-tile), full d=64. Loop j in chunks of 16.
// ---------------------------------------------------------------------------
__global__ __launch_bounds__(256) void k_attnv3(
    const short* __restrict__ qh, const short* __restrict__ kh,
    const short* __restrict__ vh,
    const float* __restrict__ mfl, const float* __restrict__ Lnv,
    short* __restrict__ xb)
{
  __shared__ float Qs[64][68];
  __shared__ float Ks[16][68];
  __shared__ float Vs[16][68];
  __shared__ float Ps[64][17];
  __shared__ float mis[64], mjs[16], Ljs[16];
  const int bh = blockIdx.y, b = bh >> 4, h = bh & (NH - 1);
  const int i0 = blockIdx.x * 64;
  const int tid = threadIdx.x;
#pragma unroll
  for (int p = 0; p < 16; ++p) {
    const int el = tid + p * 256;
    const int r = el >> 6, d = el & 63;
    Qs[r][d] = bf2f(qh[(bh * SQ + i0 + r) * HD + d]);
  }
  if (tid < 64) mis[tid] = mfl[b * SQ + i0 + tid];
  const int pr = tid >> 2, pc0 = (tid & 3) * 4;    // P-compute mapping
  const int ti = tid >> 4, td = tid & 15;          // PV mapping
  float acc[4][4] = {};
  for (int j0 = 0; j0 < SQ; j0 += 16) {
    __syncthreads();   // prior-iteration PV reads done before restage
#pragma unroll
    for (int p = 0; p < 4; ++p) {
      const int el = tid + p * 256;
      const int r = el >> 6, d = el & 63;
      Ks[r][d] = bf2f(kh[(bh * SQ + j0 + r) * HD + d]);
      Vs[r][d] = bf2f(vh[(bh * SQ + j0 + r) * HD + d]);
    }
    if (tid < 16) {
      mjs[tid] = mfl[b * SQ + j0 + tid];
      Ljs[tid] = Lnv[bh * SQ + j0 + tid];
    }
    __syncthreads();
    float dot[4] = {0.f, 0.f, 0.f, 0.f};
#pragma unroll
    for (int dv = 0; dv < 16; ++dv) {
      const f32x4 qv = *(const f32x4*)&Qs[pr][dv * 4];
#pragma unroll
      for (int c = 0; c < 4; ++c) {
        const f32x4 kv = *(const f32x4*)&Ks[pc0 + c][dv * 4];
        dot[c] = fmaf(qv[0], kv[0], dot[c]);
        dot[c] = fmaf(qv[1], kv[1], dot[c]);
        dot[c] = fmaf(qv[2], kv[2], dot[c]);
        dot[c] = fmaf(qv[3], kv[3], dot[c]);
      }
    }
#pragma unroll
    for (int c = 0; c < 4; ++c)
      Ps[pr][pc0 + c] = __expf(dot[c] * (mis[pr] * mjs[pc0 + c])) * Ljs[pc0 + c];
    __syncthreads();
#pragma unroll
    for (int jl = 0; jl < 16; ++jl) {
      const f32x4 vv = *(const f32x4*)&Vs[jl][td * 4];
#pragma unroll
      for (int r = 0; r < 4; ++r) {
        const float p = Ps[ti * 4 + r][jl];
#pragma unroll
        for (int c = 0; c < 4; ++c) acc[r][c] = fmaf(p, vv[c], acc[r][c]);
      }
    }
  }
#pragma unroll
  for (int r = 0; r < 4; ++r)
#pragma unroll
    for (int c = 0; c < 4; ++c) {
      const int i = i0 + ti * 4 + r;
      const int d = td * 4 + c;
      xb[(b * SQ + i) * HIDN + h * HD + d] = f2bf(acc[r][c]);
    }
}

// ---------------------------------------------------------------------------
// K4: out[r,c] = x[r,:]·Wo[c,:] + bo[c].  *** FP32 output to d_out. ***
// ---------------------------------------------------------------------------
__global__ __launch_bounds__(256) void k_gemm_out(
    const short* __restrict__ xb,
    const float* __restrict__ Wo, const float* __restrict__ bo,
    float* __restrict__ out)
{
  __shared__ float As[64][17];
  __shared__ float Bs[64][17];
  const int row0 = blockIdx.y * 64, col0 = blockIdx.x * 64;
  const int tid = threadIdx.x;
  const int tx = tid & 15, ty = tid >> 4;
  float acc[4][4] = {};
  for (int k0 = 0; k0 < HIDN; k0 += 16) {
#pragma unroll
    for (int p = 0; p < 4; ++p) {
      const int el = tid + p * 256;
      const int r = el >> 4, kk = el & 15;
      As[r][kk] = bf2f(xb[(row0 + r) * HIDN + k0 + kk]);
      Bs[r][kk] = Wo[(col0 + r) * HIDN + k0 + kk];
    }
    __syncthreads();
#pragma unroll
    for (int e = 0; e < 16; ++e) {
      float a[4], b[4];
#pragma unroll
      for (int i = 0; i < 4; ++i) a[i] = As[ty + 16 * i][e];
#pragma unroll
      for (int j = 0; j < 4; ++j) b[j] = Bs[tx + 16 * j][e];
#pragma unroll
      for (int i = 0; i < 4; ++i)
#pragma unroll
        for (int j = 0; j < 4; ++j) acc[i][j] = fmaf(a[i], b[j], acc[i][j]);
    }
    __syncthreads();
  }
#pragma unroll
  for (int i = 0; i < 4; ++i)
#pragma unroll
    for (int j = 0; j < 4; ++j) {
      const int row = row0 + ty + 16 * i;
      const int col = col0 + tx + 16 * j;
      out[row * HIDN + col] = acc[i][j] + bo[col];
    }
}

// ---------------------------------------------------------------------------
extern "C" void kernel_launch(void* const* d_in, const int* in_sizes, int n_in,
                              void* d_out, int out_size, void* d_ws, size_t ws_size,
                              hipStream_t stream) {
  const float* query = (const float*)d_in[0];
  const unsigned* mraw = (const unsigned*)d_in[1];
  const float* Wq = (const float*)d_in[2];
  const float* bq = (const float*)d_in[3];
  const float* Wk = (const float*)d_in[4];
  const float* bk = (const float*)d_in[5];
  const float* Wv = (const float*)d_in[6];
  const float* bv = (const float*)d_in[7];
  const float* Wo = (const float*)d_in[8];
  const float* bo = (const float*)d_in[9];

  // ws (shorts): kh 16.78M | vh 16.78M | qh 16.78M | xb 16.78M | Lnv 0.52M | mfl 32K
  short* kh  = (short*)d_ws;
  short* vh  = kh + (NB * NH * SQ * HD);
  short* qh  = vh + (NB * NH * SQ * HD);
  short* xb  = qh + (NB * NH * SQ * HD);
  float* Lnv = (float*)(xb + (NB * SQ * HIDN));
  float* mfl = Lnv + (NB * NH * SQ);

  k_maskprep<<<dim3(1), dim3(256), 0, stream>>>(mraw, mfl);
  k_gemm_qkv<<<dim3(HIDN / 64, (NB * SQ) / 64, 3), dim3(256), 0, stream>>>(
      query, Wq, bq, Wk, bk, Wv, bv, qh, kh, vh);
  k_sumexp<<<dim3(SQ / 256, NB * NH), dim3(256), 0, stream>>>(qh, kh, mfl, Lnv);
  k_attnv3<<<dim3(SQ / 64, NB * NH), dim3(256), 0, stream>>>(qh, kh, vh, mfl, Lnv, xb);
  k_gemm_out<<<dim3(HIDN / 64, (NB * SQ) / 64), dim3(256), 0, stream>>>(
      xb, Wo, bo, (float*)d_out);
}

// Round 7
// 895.687 us; speedup vs baseline: 3.9039x; 3.9039x over previous
//
#include <hip/hip_runtime.h>

#define SQ   2048
#define HIDN 1024
#define NB   4
#define NH   16
#define HD   64

typedef __attribute__((ext_vector_type(8))) short short8;
typedef __attribute__((ext_vector_type(4))) float f32x4;

__device__ __forceinline__ short f2bf(float f) {
  union { float f; unsigned u; } x; x.f = f;
  unsigned r = (x.u + 0x7fffu + ((x.u >> 16) & 1u)) >> 16;
  return (short)r;
}
__device__ __forceinline__ float bf2f(int s) {
  union { unsigned u; float f; } x;
  x.u = ((unsigned)(unsigned short)s) << 16;
  return x.f;
}

#define MFMA(a, b, c) __builtin_amdgcn_mfma_f32_16x16x32_bf16((a), (b), (c), 0, 0, 0)

// ---------------------------------------------------------------------------
// K0: normalize mask to fp32 (auto-detect int32 / byte-bool / fp32). Verified.
// ---------------------------------------------------------------------------
__global__ __launch_bounds__(256) void k_maskprep(const unsigned* __restrict__ mraw,
                                                  float* __restrict__ m) {
  __shared__ unsigned red[256];
  const int tid = threadIdx.x;
  unsigned w_or = 0;
  for (int i = tid; i < 2048; i += 256) w_or |= mraw[i];
  red[tid] = w_or;
  __syncthreads();
  for (int s = 128; s > 0; s >>= 1) {
    if (tid < s) red[tid] |= red[tid + s];
    __syncthreads();
  }
  const unsigned allw = red[0];
  int mode;
  if ((allw & 0xFFFFFFFEu) == 0) mode = 0;
  else if ((allw & 0xFEFEFEFEu) == 0) mode = 1;
  else mode = 2;
  const unsigned char* mb = (const unsigned char*)mraw;
  const float* mf = (const float*)mraw;
  const int* mi = (const int*)mraw;
  for (int i = tid; i < NB * SQ; i += 256) {
    float v;
    if (mode == 0)      v = mi[i] ? 1.0f : 0.0f;
    else if (mode == 1) v = mb[i] ? 1.0f : 0.0f;
    else                v = (mf[i] != 0.0f) ? 1.0f : 0.0f;
    m[i] = v;
  }
}

// ---------------------------------------------------------------------------
// K1: QKV projections via MFMA.  C[r,c] = query[r,:]·W[c,:] + bias[c].
// z=0: q*0.125 -> qh[b,h,s,d]; z=1: k -> kh[b,h,s,d]; z=2: v -> vT[b,h,d,s].
// 64x64 tile, 4 waves 2x2, each wave 2x2 16x16 frags, BK=32.
// ---------------------------------------------------------------------------
__global__ __launch_bounds__(256) void k_proj_qkv(
    const float* __restrict__ query,
    const float* __restrict__ Wq, const float* __restrict__ bq,
    const float* __restrict__ Wk, const float* __restrict__ bk,
    const float* __restrict__ Wv, const float* __restrict__ bv,
    short* __restrict__ qh, short* __restrict__ kh, short* __restrict__ vT)
{
  __shared__ short a_s[64][48];   // 96B row stride, 16B-aligned frag reads
  __shared__ short b_s[64][48];
  const int z = blockIdx.z;
  const float* __restrict__ W    = (z == 0) ? Wq : (z == 1) ? Wk : Wv;
  const float* __restrict__ bias = (z == 0) ? bq : (z == 1) ? bk : bv;
  const int nt = blockIdx.x, mt = blockIdx.y;
  const int tid = threadIdx.x;
  const int w = tid >> 6, lane = tid & 63;
  const int wr = w >> 1, wc = w & 1;
  const int lg = lane >> 4, lr = lane & 15;
  const int srow = tid >> 2, scol = (tid & 3) * 8;

  const float* aptr = query + (mt * 64 + srow) * HIDN + scol;
  const float* bptr = W     + (nt * 64 + srow) * HIDN + scol;

  f32x4 acc[2][2] = {};

  for (int k0 = 0; k0 < HIDN; k0 += 32) {
    f32x4 a0 = *(const f32x4*)(aptr + k0);
    f32x4 a1 = *(const f32x4*)(aptr + k0 + 4);
    f32x4 b0 = *(const f32x4*)(bptr + k0);
    f32x4 b1 = *(const f32x4*)(bptr + k0 + 4);
    short8 av, wv8;
#pragma unroll
    for (int e = 0; e < 4; ++e) { av[e] = f2bf(a0[e]); av[e + 4] = f2bf(a1[e]); }
#pragma unroll
    for (int e = 0; e < 4; ++e) { wv8[e] = f2bf(b0[e]); wv8[e + 4] = f2bf(b1[e]); }
    *(short8*)&a_s[srow][scol] = av;
    *(short8*)&b_s[srow][scol] = wv8;
    __syncthreads();
    short8 af[2], bfb[2];
#pragma unroll
    for (int mi = 0; mi < 2; ++mi)
      af[mi] = *(const short8*)&a_s[wr * 32 + mi * 16 + lr][lg * 8];
#pragma unroll
    for (int ni = 0; ni < 2; ++ni)
      bfb[ni] = *(const short8*)&b_s[wc * 32 + ni * 16 + lr][lg * 8];
#pragma unroll
    for (int mi = 0; mi < 2; ++mi)
#pragma unroll
      for (int ni = 0; ni < 2; ++ni)
        acc[mi][ni] = MFMA(af[mi], bfb[ni], acc[mi][ni]);
    __syncthreads();
  }

#pragma unroll
  for (int mi = 0; mi < 2; ++mi)
#pragma unroll
    for (int ni = 0; ni < 2; ++ni)
#pragma unroll
      for (int r = 0; r < 4; ++r) {
        const int row = mt * 64 + wr * 32 + mi * 16 + lg * 4 + r;  // [0,8192)
        const int col = nt * 64 + wc * 32 + ni * 16 + lr;          // [0,1024)
        const float v = acc[mi][ni][r] + bias[col];
        const int bi = row >> 11, s = row & (SQ - 1);
        const int h = col >> 6, d = col & (HD - 1);
        if (z == 0) {
          qh[(((bi * NH + h) * SQ + s) * HD) + d] = f2bf(v * 0.125f);
        } else if (z == 1) {
          kh[(((bi * NH + h) * SQ + s) * HD) + d] = f2bf(v);
        } else {
          vT[(((bi * NH + h) * HD + d) * SQ) + s] = f2bf(v);
        }
      }
}

// ---------------------------------------------------------------------------
// K2: per-column (query-axis) softmax denominators via MFMA.
// Lnv[j] = 1 / sum_i exp((q_i·k_j)*mi*mj).  No max-shift (|E|<=~4, validated).
// Block = 64 cols (4 waves x 16); wave iterates all 2048 rows, 16 per MFMA.
// ---------------------------------------------------------------------------
__global__ __launch_bounds__(256) void k_sumexp_m(
    const short* __restrict__ qh, const short* __restrict__ kh,
    const float* __restrict__ mfl, float* __restrict__ Lnv)
{
  __shared__ float m_s[SQ];
  const int bh = blockIdx.y, b = bh >> 4;
  const int jt = blockIdx.x;
  const int tid = threadIdx.x, w = tid >> 6, lane = tid & 63;
  const int lg = lane >> 4, lr = lane & 15;
  for (int i = tid; i < SQ; i += 256) m_s[i] = mfl[b * SQ + i];
  __syncthreads();

  const int base = bh * SQ * HD;
  const int j = jt * 64 + w * 16 + lr;
  const short8 bk0 = *(const short8*)(kh + base + j * HD + lg * 8);
  const short8 bk1 = *(const short8*)(kh + base + j * HD + 32 + lg * 8);
  const float mj = m_s[j];

  float L = 0.f;
  for (int ib = 0; ib < SQ; ib += 16) {
    const short8 a0 = *(const short8*)(qh + base + (ib + lr) * HD + lg * 8);
    const short8 a1 = *(const short8*)(qh + base + (ib + lr) * HD + 32 + lg * 8);
    f32x4 e = {};
    e = MFMA(a0, bk0, e);
    e = MFMA(a1, bk1, e);
#pragma unroll
    for (int r = 0; r < 4; ++r)
      L += __expf(e[r] * (m_s[ib + lg * 4 + r] * mj));
  }
  // sum the 4 lane-groups (same j for lanes sharing lr)
  L += __shfl_xor(L, 16, 64);
  L += __shfl_xor(L, 32, 64);
  if (lg == 0) Lnv[bh * SQ + j] = 1.0f / L;
}

// ---------------------------------------------------------------------------
// K3: x[i,d] = sum_j exp(E[i,j]*mi*mj) * Lnv[j] * v[j,d] via MFMA.
// Block = 64 rows (4 waves x 16); j in steps of 32; P through wave-private LDS
// to convert D-frag -> A-frag layout; PV with vT as B_T.
// ---------------------------------------------------------------------------
__global__ __launch_bounds__(256) void k_attnv(
    const short* __restrict__ qh, const short* __restrict__ kh,
    const short* __restrict__ vT,
    const float* __restrict__ mfl, const float* __restrict__ Lnv,
    short* __restrict__ xo)
{
  __shared__ float m_s[SQ];
  __shared__ short p_s[4][16][48];
  const int bh = blockIdx.y, b = bh >> 4, h = bh & (NH - 1);
  const int it = blockIdx.x;
  const int tid = threadIdx.x, w = tid >> 6, lane = tid & 63;
  const int lg = lane >> 4, lr = lane & 15;
  for (int i = tid; i < SQ; i += 256) m_s[i] = mfl[b * SQ + i];
  __syncthreads();

  const int base = bh * SQ * HD;   // == bh*HD*SQ for vT
  const int sb = bh * SQ;
  const int i0 = it * 64 + w * 16;
  const short8 aq0 = *(const short8*)(qh + base + (i0 + lr) * HD + lg * 8);
  const short8 aq1 = *(const short8*)(qh + base + (i0 + lr) * HD + 32 + lg * 8);
  float mi[4];
#pragma unroll
  for (int r = 0; r < 4; ++r) mi[r] = m_s[i0 + lg * 4 + r];

  f32x4 accx[4] = {};
  for (int jb = 0; jb < SQ; jb += 32) {
#pragma unroll
    for (int jj = 0; jj < 2; ++jj) {
      const int j = jb + jj * 16 + lr;
      const short8 bk0 = *(const short8*)(kh + base + j * HD + lg * 8);
      const short8 bk1 = *(const short8*)(kh + base + j * HD + 32 + lg * 8);
      f32x4 e = {};
      e = MFMA(aq0, bk0, e);
      e = MFMA(aq1, bk1, e);
      const float mj = m_s[j];
      const float Lj = Lnv[sb + j];
#pragma unroll
      for (int r = 0; r < 4; ++r) {
        const float p = __expf(e[r] * (mi[r] * mj)) * Lj;
        p_s[w][lg * 4 + r][jj * 16 + lr] = f2bf(p);
      }
    }
    const short8 pa = *(const short8*)&p_s[w][lr][lg * 8];
#pragma unroll
    for (int nd = 0; nd < 4; ++nd) {
      const short8 bv = *(const short8*)(vT + base + (nd * 16 + lr) * SQ + jb + lg * 8);
      accx[nd] = MFMA(pa, bv, accx[nd]);
    }
  }
#pragma unroll
  for (int nd = 0; nd < 4; ++nd)
#pragma unroll
    for (int r = 0; r < 4; ++r) {
      const int i = i0 + lg * 4 + r, d = nd * 16 + lr;
      xo[(b * SQ + i) * HIDN + h * HD + d] = f2bf(accx[nd][r]);
    }
}

// ---------------------------------------------------------------------------
// K4: out[r,c] = x[r,:]·Wo[c,:] + bo[c] via MFMA.  FP32 output to d_out.
// ---------------------------------------------------------------------------
__global__ __launch_bounds__(256) void k_proj_out(
    const short* __restrict__ x,
    const float* __restrict__ Wo, const float* __restrict__ bo,
    float* __restrict__ out)
{
  __shared__ short a_s[64][48];
  __shared__ short b_s[64][48];
  const int nt = blockIdx.x, mt = blockIdx.y;
  const int tid = threadIdx.x;
  const int w = tid >> 6, lane = tid & 63;
  const int wr = w >> 1, wc = w & 1;
  const int lg = lane >> 4, lr = lane & 15;
  const int srow = tid >> 2, scol = (tid & 3) * 8;

  const short* aptr = x + (mt * 64 + srow) * HIDN + scol;
  const float* bptr = Wo + (nt * 64 + srow) * HIDN + scol;

  f32x4 acc[2][2] = {};

  for (int k0 = 0; k0 < HIDN; k0 += 32) {
    const short8 av = *(const short8*)(aptr + k0);
    f32x4 b0 = *(const f32x4*)(bptr + k0);
    f32x4 b1 = *(const f32x4*)(bptr + k0 + 4);
    short8 wv8;
#pragma unroll
    for (int e = 0; e < 4; ++e) { wv8[e] = f2bf(b0[e]); wv8[e + 4] = f2bf(b1[e]); }
    *(short8*)&a_s[srow][scol] = av;
    *(short8*)&b_s[srow][scol] = wv8;
    __syncthreads();
    short8 af[2], bfb[2];
#pragma unroll
    for (int mi = 0; mi < 2; ++mi)
      af[mi] = *(const short8*)&a_s[wr * 32 + mi * 16 + lr][lg * 8];
#pragma unroll
    for (int ni = 0; ni < 2; ++ni)
      bfb[ni] = *(const short8*)&b_s[wc * 32 + ni * 16 + lr][lg * 8];
#pragma unroll
    for (int mi = 0; mi < 2; ++mi)
#pragma unroll
      for (int ni = 0; ni < 2; ++ni)
        acc[mi][ni] = MFMA(af[mi], bfb[ni], acc[mi][ni]);
    __syncthreads();
  }

#pragma unroll
  for (int mi = 0; mi < 2; ++mi)
#pragma unroll
    for (int ni = 0; ni < 2; ++ni)
#pragma unroll
      for (int r = 0; r < 4; ++r) {
        const int row = mt * 64 + wr * 32 + mi * 16 + lg * 4 + r;
        const int col = nt * 64 + wc * 32 + ni * 16 + lr;
        out[row * HIDN + col] = acc[mi][ni][r] + bo[col];
      }
}

// ---------------------------------------------------------------------------
extern "C" void kernel_launch(void* const* d_in, const int* in_sizes, int n_in,
                              void* d_out, int out_size, void* d_ws, size_t ws_size,
                              hipStream_t stream) {
  const float* query = (const float*)d_in[0];
  const unsigned* mraw = (const unsigned*)d_in[1];
  const float* Wq = (const float*)d_in[2];
  const float* bq = (const float*)d_in[3];
  const float* Wk = (const float*)d_in[4];
  const float* bk = (const float*)d_in[5];
  const float* Wv = (const float*)d_in[6];
  const float* bv = (const float*)d_in[7];
  const float* Wo = (const float*)d_in[8];
  const float* bo = (const float*)d_in[9];

  // ws (shorts): qh 16.78M | kh 16.78M | vT 16.78M | xb 16.78M | Lnv 0.52M | mfl 32K
  short* qh  = (short*)d_ws;
  short* kh  = qh + (NB * NH * SQ * HD);
  short* vT  = kh + (NB * NH * SQ * HD);
  short* xb  = vT + (NB * NH * SQ * HD);
  float* Lnv = (float*)(xb + (NB * SQ * HIDN));
  float* mfl = Lnv + (NB * NH * SQ);

  k_maskprep<<<dim3(1), dim3(256), 0, stream>>>(mraw, mfl);
  k_proj_qkv<<<dim3(HIDN / 64, (NB * SQ) / 64, 3), dim3(256), 0, stream>>>(
      query, Wq, bq, Wk, bk, Wv, bv, qh, kh, vT);
  k_sumexp_m<<<dim3(SQ / 64, NB * NH), dim3(256), 0, stream>>>(qh, kh, mfl, Lnv);
  k_attnv<<<dim3(SQ / 64, NB * NH), dim3(256), 0, stream>>>(qh, kh, vT, mfl, Lnv, xb);
  k_proj_out<<<dim3(HIDN / 64, (NB * SQ) / 64), dim3(256), 0, stream>>>(
      xb, Wo, bo, (float*)d_out);
}

// Round 8
// 565.080 us; speedup vs baseline: 6.1879x; 1.5851x over previous
//
#include <hip/hip_runtime.h>

#define SQ   2048
#define HIDN 1024
#define NB   4
#define NH   16
#define HD   64

typedef __attribute__((ext_vector_type(8))) short short8;
typedef __attribute__((ext_vector_type(4))) float f32x4;

__device__ __forceinline__ short f2bf(float f) {
  union { float f; unsigned u; } x; x.f = f;
  unsigned r = (x.u + 0x7fffu + ((x.u >> 16) & 1u)) >> 16;
  return (short)r;
}

#define MFMA(a, b, c) __builtin_amdgcn_mfma_f32_16x16x32_bf16((a), (b), (c), 0, 0, 0)

// ---------------------------------------------------------------------------
// K0: normalize mask to fp32 (auto-detect int32 / byte-bool / fp32). Verified.
// ---------------------------------------------------------------------------
__global__ __launch_bounds__(256) void k_maskprep(const unsigned* __restrict__ mraw,
                                                  float* __restrict__ m) {
  __shared__ unsigned red[256];
  const int tid = threadIdx.x;
  unsigned w_or = 0;
  for (int i = tid; i < 2048; i += 256) w_or |= mraw[i];
  red[tid] = w_or;
  __syncthreads();
  for (int s = 128; s > 0; s >>= 1) {
    if (tid < s) red[tid] |= red[tid + s];
    __syncthreads();
  }
  const unsigned allw = red[0];
  int mode;
  if ((allw & 0xFFFFFFFEu) == 0) mode = 0;
  else if ((allw & 0xFEFEFEFEu) == 0) mode = 1;
  else mode = 2;
  const unsigned char* mb = (const unsigned char*)mraw;
  const float* mf = (const float*)mraw;
  const int* mi = (const int*)mraw;
  for (int i = tid; i < NB * SQ; i += 256) {
    float v;
    if (mode == 0)      v = mi[i] ? 1.0f : 0.0f;
    else if (mode == 1) v = mb[i] ? 1.0f : 0.0f;
    else                v = (mf[i] != 0.0f) ? 1.0f : 0.0f;
    m[i] = v;
  }
}

// ---------------------------------------------------------------------------
// K1: QKV projections via MFMA (verified round 7, unchanged).
// ---------------------------------------------------------------------------
__global__ __launch_bounds__(256) void k_proj_qkv(
    const float* __restrict__ query,
    const float* __restrict__ Wq, const float* __restrict__ bq,
    const float* __restrict__ Wk, const float* __restrict__ bk,
    const float* __restrict__ Wv, const float* __restrict__ bv,
    short* __restrict__ qh, short* __restrict__ kh, short* __restrict__ vT)
{
  __shared__ short a_s[64][48];
  __shared__ short b_s[64][48];
  const int z = blockIdx.z;
  const float* __restrict__ W    = (z == 0) ? Wq : (z == 1) ? Wk : Wv;
  const float* __restrict__ bias = (z == 0) ? bq : (z == 1) ? bk : bv;
  const int nt = blockIdx.x, mt = blockIdx.y;
  const int tid = threadIdx.x;
  const int w = tid >> 6, lane = tid & 63;
  const int wr = w >> 1, wc = w & 1;
  const int lg = lane >> 4, lr = lane & 15;
  const int srow = tid >> 2, scol = (tid & 3) * 8;

  const float* aptr = query + (mt * 64 + srow) * HIDN + scol;
  const float* bptr = W     + (nt * 64 + srow) * HIDN + scol;

  f32x4 acc[2][2] = {};

  for (int k0 = 0; k0 < HIDN; k0 += 32) {
    f32x4 a0 = *(const f32x4*)(aptr + k0);
    f32x4 a1 = *(const f32x4*)(aptr + k0 + 4);
    f32x4 b0 = *(const f32x4*)(bptr + k0);
    f32x4 b1 = *(const f32x4*)(bptr + k0 + 4);
    short8 av, wv8;
#pragma unroll
    for (int e = 0; e < 4; ++e) { av[e] = f2bf(a0[e]); av[e + 4] = f2bf(a1[e]); }
#pragma unroll
    for (int e = 0; e < 4; ++e) { wv8[e] = f2bf(b0[e]); wv8[e + 4] = f2bf(b1[e]); }
    *(short8*)&a_s[srow][scol] = av;
    *(short8*)&b_s[srow][scol] = wv8;
    __syncthreads();
    short8 af[2], bfb[2];
#pragma unroll
    for (int mi = 0; mi < 2; ++mi)
      af[mi] = *(const short8*)&a_s[wr * 32 + mi * 16 + lr][lg * 8];
#pragma unroll
    for (int ni = 0; ni < 2; ++ni)
      bfb[ni] = *(const short8*)&b_s[wc * 32 + ni * 16 + lr][lg * 8];
#pragma unroll
    for (int mi = 0; mi < 2; ++mi)
#pragma unroll
      for (int ni = 0; ni < 2; ++ni)
        acc[mi][ni] = MFMA(af[mi], bfb[ni], acc[mi][ni]);
    __syncthreads();
  }

#pragma unroll
  for (int mi = 0; mi < 2; ++mi)
#pragma unroll
    for (int ni = 0; ni < 2; ++ni)
#pragma unroll
      for (int r = 0; r < 4; ++r) {
        const int row = mt * 64 + wr * 32 + mi * 16 + lg * 4 + r;
        const int col = nt * 64 + wc * 32 + ni * 16 + lr;
        const float v = acc[mi][ni][r] + bias[col];
        const int bi = row >> 11, s = row & (SQ - 1);
        const int h = col >> 6, d = col & (HD - 1);
        if (z == 0) {
          qh[(((bi * NH + h) * SQ + s) * HD) + d] = f2bf(v * 0.125f);
        } else if (z == 1) {
          kh[(((bi * NH + h) * SQ + s) * HD) + d] = f2bf(v);
        } else {
          vT[(((bi * NH + h) * HD + d) * SQ) + s] = f2bf(v);
        }
      }
}

// ---------------------------------------------------------------------------
// K2: per-column softmax denominators, ib batched x4 for ILP.
// Lnv[j] = 1 / sum_i exp((q_i·k_j)*mi*mj).  Fragment math identical to r7.
// ---------------------------------------------------------------------------
__global__ __launch_bounds__(256) void k_sumexp_m(
    const short* __restrict__ qh, const short* __restrict__ kh,
    const float* __restrict__ mfl, float* __restrict__ Lnv)
{
  __shared__ float m_s[SQ];
  const int bh = blockIdx.y, b = bh >> 4;
  const int jt = blockIdx.x;
  const int tid = threadIdx.x, w = tid >> 6, lane = tid & 63;
  const int lg = lane >> 4, lr = lane & 15;
  for (int i = tid; i < SQ; i += 256) m_s[i] = mfl[b * SQ + i];
  __syncthreads();

  const int base = bh * SQ * HD;
  const int j = jt * 64 + w * 16 + lr;
  const short8 bk0 = *(const short8*)(kh + base + j * HD + lg * 8);
  const short8 bk1 = *(const short8*)(kh + base + j * HD + 32 + lg * 8);
  const float mj = m_s[j];

  float L = 0.f;
  for (int ib = 0; ib < SQ; ib += 64) {
    f32x4 e[4];
#pragma unroll
    for (int s = 0; s < 4; ++s) {
      const short8 a0 = *(const short8*)(qh + base + (ib + s * 16 + lr) * HD + lg * 8);
      const short8 a1 = *(const short8*)(qh + base + (ib + s * 16 + lr) * HD + 32 + lg * 8);
      f32x4 ee = {};
      ee = MFMA(a0, bk0, ee);
      ee = MFMA(a1, bk1, ee);
      e[s] = ee;
    }
#pragma unroll
    for (int s = 0; s < 4; ++s)
#pragma unroll
      for (int r = 0; r < 4; ++r)
        L += __expf(e[s][r] * (m_s[ib + s * 16 + lg * 4 + r] * mj));
  }
  L += __shfl_xor(L, 16, 64);
  L += __shfl_xor(L, 32, 64);
  if (lg == 0) Lnv[bh * SQ + j] = 1.0f / L;
}

// ---------------------------------------------------------------------------
// K3: attention-weighted V.  Wave owns 64 rows (4 i-frags); block = 256 rows.
// Per jb=32 step: 16 QK MFMA (8 indep chains) + 16 indep PV MFMA; kh/vT loads
// amortized over 4 i-frags; no __syncthreads in loop (p_s wave-private).
// ---------------------------------------------------------------------------
__global__ __launch_bounds__(256) void k_attnv(
    const short* __restrict__ qh, const short* __restrict__ kh,
    const short* __restrict__ vT,
    const float* __restrict__ mfl, const float* __restrict__ Lnv,
    short* __restrict__ xo)
{
  __shared__ float m_s[SQ];
  __shared__ float L_s[SQ];
  __shared__ short p_s[4][4][16][40];   // [wave][fi][row][col], 80B rows (16B-aligned)
  const int bh = blockIdx.y, b = bh >> 4, h = bh & (NH - 1);
  const int it = blockIdx.x;
  const int tid = threadIdx.x, w = tid >> 6, lane = tid & 63;
  const int lg = lane >> 4, lr = lane & 15;
  for (int i = tid; i < SQ; i += 256) {
    m_s[i] = mfl[b * SQ + i];
    L_s[i] = Lnv[bh * SQ + i];
  }
  __syncthreads();

  const int base = bh * SQ * HD;   // == bh*HD*SQ for vT
  const int i0 = it * 256 + w * 64;

  short8 aq[4][2];
  float mi[4][4];
#pragma unroll
  for (int fi = 0; fi < 4; ++fi) {
    aq[fi][0] = *(const short8*)(qh + base + (i0 + fi * 16 + lr) * HD + lg * 8);
    aq[fi][1] = *(const short8*)(qh + base + (i0 + fi * 16 + lr) * HD + 32 + lg * 8);
#pragma unroll
    for (int r = 0; r < 4; ++r) mi[fi][r] = m_s[i0 + fi * 16 + lg * 4 + r];
  }

  f32x4 accx[4][4] = {};
  for (int jb = 0; jb < SQ; jb += 32) {
    short8 bk[2][2];
#pragma unroll
    for (int jj = 0; jj < 2; ++jj) {
      const int j = jb + jj * 16 + lr;
      bk[jj][0] = *(const short8*)(kh + base + j * HD + lg * 8);
      bk[jj][1] = *(const short8*)(kh + base + j * HD + 32 + lg * 8);
    }
    short8 bv[4];
#pragma unroll
    for (int nd = 0; nd < 4; ++nd)
      bv[nd] = *(const short8*)(vT + base + (nd * 16 + lr) * SQ + jb + lg * 8);

#pragma unroll
    for (int fi = 0; fi < 4; ++fi) {
#pragma unroll
      for (int jj = 0; jj < 2; ++jj) {
        f32x4 e = {};
        e = MFMA(aq[fi][0], bk[jj][0], e);
        e = MFMA(aq[fi][1], bk[jj][1], e);
        const float mjv = m_s[jb + jj * 16 + lr];
        const float Ljv = L_s[jb + jj * 16 + lr];
#pragma unroll
        for (int r = 0; r < 4; ++r) {
          const float p = __expf(e[r] * (mi[fi][r] * mjv)) * Ljv;
          p_s[w][fi][lg * 4 + r][jj * 16 + lr] = f2bf(p);
        }
      }
    }
#pragma unroll
    for (int fi = 0; fi < 4; ++fi) {
      const short8 pa = *(const short8*)&p_s[w][fi][lr][lg * 8];
#pragma unroll
      for (int nd = 0; nd < 4; ++nd)
        accx[fi][nd] = MFMA(pa, bv[nd], accx[fi][nd]);
    }
  }

#pragma unroll
  for (int fi = 0; fi < 4; ++fi)
#pragma unroll
    for (int nd = 0; nd < 4; ++nd)
#pragma unroll
      for (int r = 0; r < 4; ++r) {
        const int i = i0 + fi * 16 + lg * 4 + r, d = nd * 16 + lr;
        xo[(b * SQ + i) * HIDN + h * HD + d] = f2bf(accx[fi][nd][r]);
      }
}

// ---------------------------------------------------------------------------
// K4: output projection via MFMA (verified round 7, unchanged). FP32 out.
// ---------------------------------------------------------------------------
__global__ __launch_bounds__(256) void k_proj_out(
    const short* __restrict__ x,
    const float* __restrict__ Wo, const float* __restrict__ bo,
    float* __restrict__ out)
{
  __shared__ short a_s[64][48];
  __shared__ short b_s[64][48];
  const int nt = blockIdx.x, mt = blockIdx.y;
  const int tid = threadIdx.x;
  const int w = tid >> 6, lane = tid & 63;
  const int wr = w >> 1, wc = w & 1;
  const int lg = lane >> 4, lr = lane & 15;
  const int srow = tid >> 2, scol = (tid & 3) * 8;

  const short* aptr = x + (mt * 64 + srow) * HIDN + scol;
  const float* bptr = Wo + (nt * 64 + srow) * HIDN + scol;

  f32x4 acc[2][2] = {};

  for (int k0 = 0; k0 < HIDN; k0 += 32) {
    const short8 av = *(const short8*)(aptr + k0);
    f32x4 b0 = *(const f32x4*)(bptr + k0);
    f32x4 b1 = *(const f32x4*)(bptr + k0 + 4);
    short8 wv8;
#pragma unroll
    for (int e = 0; e < 4; ++e) { wv8[e] = f2bf(b0[e]); wv8[e + 4] = f2bf(b1[e]); }
    *(short8*)&a_s[srow][scol] = av;
    *(short8*)&b_s[srow][scol] = wv8;
    __syncthreads();
    short8 af[2], bfb[2];
#pragma unroll
    for (int mi = 0; mi < 2; ++mi)
      af[mi] = *(const short8*)&a_s[wr * 32 + mi * 16 + lr][lg * 8];
#pragma unroll
    for (int ni = 0; ni < 2; ++ni)
      bfb[ni] = *(const short8*)&b_s[wc * 32 + ni * 16 + lr][lg * 8];
#pragma unroll
    for (int mi = 0; mi < 2; ++mi)
#pragma unroll
      for (int ni = 0; ni < 2; ++ni)
        acc[mi][ni] = MFMA(af[mi], bfb[ni], acc[mi][ni]);
    __syncthreads();
  }

#pragma unroll
  for (int mi = 0; mi < 2; ++mi)
#pragma unroll
    for (int ni = 0; ni < 2; ++ni)
#pragma unroll
      for (int r = 0; r < 4; ++r) {
        const int row = mt * 64 + wr * 32 + mi * 16 + lg * 4 + r;
        const int col = nt * 64 + wc * 32 + ni * 16 + lr;
        out[row * HIDN + col] = acc[mi][ni][r] + bo[col];
      }
}

// ---------------------------------------------------------------------------
extern "C" void kernel_launch(void* const* d_in, const int* in_sizes, int n_in,
                              void* d_out, int out_size, void* d_ws, size_t ws_size,
                              hipStream_t stream) {
  const float* query = (const float*)d_in[0];
  const unsigned* mraw = (const unsigned*)d_in[1];
  const float* Wq = (const float*)d_in[2];
  const float* bq = (const float*)d_in[3];
  const float* Wk = (const float*)d_in[4];
  const float* bk = (const float*)d_in[5];
  const float* Wv = (const float*)d_in[6];
  const float* bv = (const float*)d_in[7];
  const float* Wo = (const float*)d_in[8];
  const float* bo = (const float*)d_in[9];

  // ws (shorts): qh 16.78M | kh 16.78M | vT 16.78M | xb 16.78M | Lnv 0.52M | mfl 32K
  short* qh  = (short*)d_ws;
  short* kh  = qh + (NB * NH * SQ * HD);
  short* vT  = kh + (NB * NH * SQ * HD);
  short* xb  = vT + (NB * NH * SQ * HD);
  float* Lnv = (float*)(xb + (NB * SQ * HIDN));
  float* mfl = Lnv + (NB * NH * SQ);

  k_maskprep<<<dim3(1), dim3(256), 0, stream>>>(mraw, mfl);
  k_proj_qkv<<<dim3(HIDN / 64, (NB * SQ) / 64, 3), dim3(256), 0, stream>>>(
      query, Wq, bq, Wk, bk, Wv, bv, qh, kh, vT);
  k_sumexp_m<<<dim3(SQ / 64, NB * NH), dim3(256), 0, stream>>>(qh, kh, mfl, Lnv);
  k_attnv<<<dim3(SQ / 256, NB * NH), dim3(256), 0, stream>>>(qh, kh, vT, mfl, Lnv, xb);
  k_proj_out<<<dim3(HIDN / 64, (NB * SQ) / 64), dim3(256), 0, stream>>>(
      xb, Wo, bo, (float*)d_out);
}

// Round 9
// 410.333 us; speedup vs baseline: 8.5215x; 1.3771x over previous
//
#include <hip/hip_runtime.h>

#define SQ   2048
#define HIDN 1024
#define NB   4
#define NH   16
#define HD   64

typedef __attribute__((ext_vector_type(8))) short short8;
typedef __attribute__((ext_vector_type(4))) float f32x4;

__device__ __forceinline__ short f2bf(float f) {
  union { float f; unsigned u; } x; x.f = f;
  unsigned r = (x.u + 0x7fffu + ((x.u >> 16) & 1u)) >> 16;
  return (short)r;
}

#define MFMA(a, b, c) __builtin_amdgcn_mfma_f32_16x16x32_bf16((a), (b), (c), 0, 0, 0)

// ---------------------------------------------------------------------------
// K0: normalize mask to fp32 (auto-detect int32 / byte-bool / fp32). Verified.
// ---------------------------------------------------------------------------
__global__ __launch_bounds__(256) void k_maskprep(const unsigned* __restrict__ mraw,
                                                  float* __restrict__ m) {
  __shared__ unsigned red[256];
  const int tid = threadIdx.x;
  unsigned w_or = 0;
  for (int i = tid; i < 2048; i += 256) w_or |= mraw[i];
  red[tid] = w_or;
  __syncthreads();
  for (int s = 128; s > 0; s >>= 1) {
    if (tid < s) red[tid] |= red[tid + s];
    __syncthreads();
  }
  const unsigned allw = red[0];
  int mode;
  if ((allw & 0xFFFFFFFEu) == 0) mode = 0;
  else if ((allw & 0xFEFEFEFEu) == 0) mode = 1;
  else mode = 2;
  const unsigned char* mb = (const unsigned char*)mraw;
  const float* mf = (const float*)mraw;
  const int* mi = (const int*)mraw;
  for (int i = tid; i < NB * SQ; i += 256) {
    float v;
    if (mode == 0)      v = mi[i] ? 1.0f : 0.0f;
    else if (mode == 1) v = mb[i] ? 1.0f : 0.0f;
    else                v = (mf[i] != 0.0f) ? 1.0f : 0.0f;
    m[i] = v;
  }
}

// ---------------------------------------------------------------------------
// K1: QKV projections via MFMA (verified, unchanged).
// ---------------------------------------------------------------------------
__global__ __launch_bounds__(256) void k_proj_qkv(
    const float* __restrict__ query,
    const float* __restrict__ Wq, const float* __restrict__ bq,
    const float* __restrict__ Wk, const float* __restrict__ bk,
    const float* __restrict__ Wv, const float* __restrict__ bv,
    short* __restrict__ qh, short* __restrict__ kh, short* __restrict__ vT)
{
  __shared__ short a_s[64][48];
  __shared__ short b_s[64][48];
  const int z = blockIdx.z;
  const float* __restrict__ W    = (z == 0) ? Wq : (z == 1) ? Wk : Wv;
  const float* __restrict__ bias = (z == 0) ? bq : (z == 1) ? bk : bv;
  const int nt = blockIdx.x, mt = blockIdx.y;
  const int tid = threadIdx.x;
  const int w = tid >> 6, lane = tid & 63;
  const int wr = w >> 1, wc = w & 1;
  const int lg = lane >> 4, lr = lane & 15;
  const int srow = tid >> 2, scol = (tid & 3) * 8;

  const float* aptr = query + (mt * 64 + srow) * HIDN + scol;
  const float* bptr = W     + (nt * 64 + srow) * HIDN + scol;

  f32x4 acc[2][2] = {};

  for (int k0 = 0; k0 < HIDN; k0 += 32) {
    f32x4 a0 = *(const f32x4*)(aptr + k0);
    f32x4 a1 = *(const f32x4*)(aptr + k0 + 4);
    f32x4 b0 = *(const f32x4*)(bptr + k0);
    f32x4 b1 = *(const f32x4*)(bptr + k0 + 4);
    short8 av, wv8;
#pragma unroll
    for (int e = 0; e < 4; ++e) { av[e] = f2bf(a0[e]); av[e + 4] = f2bf(a1[e]); }
#pragma unroll
    for (int e = 0; e < 4; ++e) { wv8[e] = f2bf(b0[e]); wv8[e + 4] = f2bf(b1[e]); }
    *(short8*)&a_s[srow][scol] = av;
    *(short8*)&b_s[srow][scol] = wv8;
    __syncthreads();
    short8 af[2], bfb[2];
#pragma unroll
    for (int mi = 0; mi < 2; ++mi)
      af[mi] = *(const short8*)&a_s[wr * 32 + mi * 16 + lr][lg * 8];
#pragma unroll
    for (int ni = 0; ni < 2; ++ni)
      bfb[ni] = *(const short8*)&b_s[wc * 32 + ni * 16 + lr][lg * 8];
#pragma unroll
    for (int mi = 0; mi < 2; ++mi)
#pragma unroll
      for (int ni = 0; ni < 2; ++ni)
        acc[mi][ni] = MFMA(af[mi], bfb[ni], acc[mi][ni]);
    __syncthreads();
  }

#pragma unroll
  for (int mi = 0; mi < 2; ++mi)
#pragma unroll
    for (int ni = 0; ni < 2; ++ni)
#pragma unroll
      for (int r = 0; r < 4; ++r) {
        const int row = mt * 64 + wr * 32 + mi * 16 + lg * 4 + r;
        const int col = nt * 64 + wc * 32 + ni * 16 + lr;
        const float v = acc[mi][ni][r] + bias[col];
        const int bi = row >> 11, s = row & (SQ - 1);
        const int h = col >> 6, d = col & (HD - 1);
        if (z == 0) {
          qh[(((bi * NH + h) * SQ + s) * HD) + d] = f2bf(v * 0.125f);
        } else if (z == 1) {
          kh[(((bi * NH + h) * SQ + s) * HD) + d] = f2bf(v);
        } else {
          vT[(((bi * NH + h) * HD + d) * SQ) + s] = f2bf(v);
        }
      }
}

// ---------------------------------------------------------------------------
// K2 v2: per-column softmax denominators.
// Block = 256 cols (wave: 64 cols = 4 j-frags, K-frags resident in VGPR).
// Q staged cooperatively in double-buffered LDS [64][72] (144B rows: aligned,
// uniform bank spread); next tile's global loads issued before compute.
// 16 independent accumulation chains per lane.
// ---------------------------------------------------------------------------
__global__ __launch_bounds__(256) void k_sumexp_m(
    const short* __restrict__ qh, const short* __restrict__ kh,
    const float* __restrict__ mfl, float* __restrict__ Lnv)
{
  __shared__ float m_s[SQ];
  __shared__ short q_s[2][64][72];
  const int bh = blockIdx.y, b = bh >> 4;
  const int jt = blockIdx.x;
  const int tid = threadIdx.x, w = tid >> 6, lane = tid & 63;
  const int lg = lane >> 4, lr = lane & 15;
  for (int i = tid; i < SQ; i += 256) m_s[i] = mfl[b * SQ + i];

  const int base = bh * SQ * HD;
  const int jbase = jt * 256 + w * 64;

  short8 bk[4][2];
#pragma unroll
  for (int jf = 0; jf < 4; ++jf) {
    const int j = jbase + jf * 16 + lr;
    bk[jf][0] = *(const short8*)(kh + base + j * HD + lg * 8);
    bk[jf][1] = *(const short8*)(kh + base + j * HD + 32 + lg * 8);
  }

  // stage tile 0 (rows 0..63): thread covers 2x16B chunks
  const int srow = tid >> 3, scc = (tid & 7) * 8;
  {
    const short8 s0 = *(const short8*)(qh + base + srow * HD + scc);
    const short8 s1 = *(const short8*)(qh + base + (32 + srow) * HD + scc);
    *(short8*)&q_s[0][srow][scc] = s0;
    *(short8*)&q_s[0][32 + srow][scc] = s1;
  }
  __syncthreads();

  float mj[4];
#pragma unroll
  for (int jf = 0; jf < 4; ++jf) mj[jf] = m_s[jbase + jf * 16 + lr];

  f32x4 Lacc[4] = {};   // [jf][r] : 16 independent chains
  for (int t = 0; t < 32; ++t) {
    const int cur = t & 1;
    short8 n0, n1;
    if (t < 31) {   // issue next tile's loads before compute (latency hiding)
      const int ibn = (t + 1) * 64;
      n0 = *(const short8*)(qh + base + (ibn + srow) * HD + scc);
      n1 = *(const short8*)(qh + base + (ibn + 32 + srow) * HD + scc);
    }
    const int ib = t * 64;
#pragma unroll
    for (int s = 0; s < 4; ++s) {
      const short8 a0 = *(const short8*)&q_s[cur][s * 16 + lr][lg * 8];
      const short8 a1 = *(const short8*)&q_s[cur][s * 16 + lr][32 + lg * 8];
      float mrow[4];
#pragma unroll
      for (int r = 0; r < 4; ++r) mrow[r] = m_s[ib + s * 16 + lg * 4 + r];
#pragma unroll
      for (int jf = 0; jf < 4; ++jf) {
        f32x4 e = {};
        e = MFMA(a0, bk[jf][0], e);
        e = MFMA(a1, bk[jf][1], e);
#pragma unroll
        for (int r = 0; r < 4; ++r)
          Lacc[jf][r] += __expf(e[r] * (mrow[r] * mj[jf]));
      }
    }
    if (t < 31) {
      __syncthreads();   // all waves done reading buf cur^1 (iter t-1)
      *(short8*)&q_s[cur ^ 1][srow][scc] = n0;
      *(short8*)&q_s[cur ^ 1][32 + srow][scc] = n1;
      __syncthreads();   // writes visible before iter t+1 computes cur^1
    }
  }

#pragma unroll
  for (int jf = 0; jf < 4; ++jf) {
    float L = Lacc[jf][0] + Lacc[jf][1] + Lacc[jf][2] + Lacc[jf][3];
    L += __shfl_xor(L, 16, 64);
    L += __shfl_xor(L, 32, 64);
    if (lg == 0) Lnv[bh * SQ + jbase + jf * 16 + lr] = 1.0f / L;
  }
}

// ---------------------------------------------------------------------------
// K3: attention-weighted V (round-8 ILP version, verified, unchanged).
// ---------------------------------------------------------------------------
__global__ __launch_bounds__(256) void k_attnv(
    const short* __restrict__ qh, const short* __restrict__ kh,
    const short* __restrict__ vT,
    const float* __restrict__ mfl, const float* __restrict__ Lnv,
    short* __restrict__ xo)
{
  __shared__ float m_s[SQ];
  __shared__ float L_s[SQ];
  __shared__ short p_s[4][4][16][40];
  const int bh = blockIdx.y, b = bh >> 4, h = bh & (NH - 1);
  const int it = blockIdx.x;
  const int tid = threadIdx.x, w = tid >> 6, lane = tid & 63;
  const int lg = lane >> 4, lr = lane & 15;
  for (int i = tid; i < SQ; i += 256) {
    m_s[i] = mfl[b * SQ + i];
    L_s[i] = Lnv[bh * SQ + i];
  }
  __syncthreads();

  const int base = bh * SQ * HD;
  const int i0 = it * 256 + w * 64;

  short8 aq[4][2];
  float mi[4][4];
#pragma unroll
  for (int fi = 0; fi < 4; ++fi) {
    aq[fi][0] = *(const short8*)(qh + base + (i0 + fi * 16 + lr) * HD + lg * 8);
    aq[fi][1] = *(const short8*)(qh + base + (i0 + fi * 16 + lr) * HD + 32 + lg * 8);
#pragma unroll
    for (int r = 0; r < 4; ++r) mi[fi][r] = m_s[i0 + fi * 16 + lg * 4 + r];
  }

  f32x4 accx[4][4] = {};
  for (int jb = 0; jb < SQ; jb += 32) {
    short8 bk[2][2];
#pragma unroll
    for (int jj = 0; jj < 2; ++jj) {
      const int j = jb + jj * 16 + lr;
      bk[jj][0] = *(const short8*)(kh + base + j * HD + lg * 8);
      bk[jj][1] = *(const short8*)(kh + base + j * HD + 32 + lg * 8);
    }
    short8 bv[4];
#pragma unroll
    for (int nd = 0; nd < 4; ++nd)
      bv[nd] = *(const short8*)(vT + base + (nd * 16 + lr) * SQ + jb + lg * 8);

#pragma unroll
    for (int fi = 0; fi < 4; ++fi) {
#pragma unroll
      for (int jj = 0; jj < 2; ++jj) {
        f32x4 e = {};
        e = MFMA(aq[fi][0], bk[jj][0], e);
        e = MFMA(aq[fi][1], bk[jj][1], e);
        const float mjv = m_s[jb + jj * 16 + lr];
        const float Ljv = L_s[jb + jj * 16 + lr];
#pragma unroll
        for (int r = 0; r < 4; ++r) {
          const float p = __expf(e[r] * (mi[fi][r] * mjv)) * Ljv;
          p_s[w][fi][lg * 4 + r][jj * 16 + lr] = f2bf(p);
        }
      }
    }
#pragma unroll
    for (int fi = 0; fi < 4; ++fi) {
      const short8 pa = *(const short8*)&p_s[w][fi][lr][lg * 8];
#pragma unroll
      for (int nd = 0; nd < 4; ++nd)
        accx[fi][nd] = MFMA(pa, bv[nd], accx[fi][nd]);
    }
  }

#pragma unroll
  for (int fi = 0; fi < 4; ++fi)
#pragma unroll
    for (int nd = 0; nd < 4; ++nd)
#pragma unroll
      for (int r = 0; r < 4; ++r) {
        const int i = i0 + fi * 16 + lg * 4 + r, d = nd * 16 + lr;
        xo[(b * SQ + i) * HIDN + h * HD + d] = f2bf(accx[fi][nd][r]);
      }
}

// ---------------------------------------------------------------------------
// K4: output projection via MFMA (verified, unchanged). FP32 out.
// ---------------------------------------------------------------------------
__global__ __launch_bounds__(256) void k_proj_out(
    const short* __restrict__ x,
    const float* __restrict__ Wo, const float* __restrict__ bo,
    float* __restrict__ out)
{
  __shared__ short a_s[64][48];
  __shared__ short b_s[64][48];
  const int nt = blockIdx.x, mt = blockIdx.y;
  const int tid = threadIdx.x;
  const int w = tid >> 6, lane = tid & 63;
  const int wr = w >> 1, wc = w & 1;
  const int lg = lane >> 4, lr = lane & 15;
  const int srow = tid >> 2, scol = (tid & 3) * 8;

  const short* aptr = x + (mt * 64 + srow) * HIDN + scol;
  const float* bptr = Wo + (nt * 64 + srow) * HIDN + scol;

  f32x4 acc[2][2] = {};

  for (int k0 = 0; k0 < HIDN; k0 += 32) {
    const short8 av = *(const short8*)(aptr + k0);
    f32x4 b0 = *(const f32x4*)(bptr + k0);
    f32x4 b1 = *(const f32x4*)(bptr + k0 + 4);
    short8 wv8;
#pragma unroll
    for (int e = 0; e < 4; ++e) { wv8[e] = f2bf(b0[e]); wv8[e + 4] = f2bf(b1[e]); }
    *(short8*)&a_s[srow][scol] = av;
    *(short8*)&b_s[srow][scol] = wv8;
    __syncthreads();
    short8 af[2], bfb[2];
#pragma unroll
    for (int mi = 0; mi < 2; ++mi)
      af[mi] = *(const short8*)&a_s[wr * 32 + mi * 16 + lr][lg * 8];
#pragma unroll
    for (int ni = 0; ni < 2; ++ni)
      bfb[ni] = *(const short8*)&b_s[wc * 32 + ni * 16 + lr][lg * 8];
#pragma unroll
    for (int mi = 0; mi < 2; ++mi)
#pragma unroll
      for (int ni = 0; ni < 2; ++ni)
        acc[mi][ni] = MFMA(af[mi], bfb[ni], acc[mi][ni]);
    __syncthreads();
  }

#pragma unroll
  for (int mi = 0; mi < 2; ++mi)
#pragma unroll
    for (int ni = 0; ni < 2; ++ni)
#pragma unroll
      for (int r = 0; r < 4; ++r) {
        const int row = mt * 64 + wr * 32 + mi * 16 + lg * 4 + r;
        const int col = nt * 64 + wc * 32 + ni * 16 + lr;
        out[row * HIDN + col] = acc[mi][ni][r] + bo[col];
      }
}

// ---------------------------------------------------------------------------
extern "C" void kernel_launch(void* const* d_in, const int* in_sizes, int n_in,
                              void* d_out, int out_size, void* d_ws, size_t ws_size,
                              hipStream_t stream) {
  const float* query = (const float*)d_in[0];
  const unsigned* mraw = (const unsigned*)d_in[1];
  const float* Wq = (const float*)d_in[2];
  const float* bq = (const float*)d_in[3];
  const float* Wk = (const float*)d_in[4];
  const float* bk = (const float*)d_in[5];
  const float* Wv = (const float*)d_in[6];
  const float* bv = (const float*)d_in[7];
  const float* Wo = (const float*)d_in[8];
  const float* bo = (const float*)d_in[9];

  // ws (shorts): qh 16.78M | kh 16.78M | vT 16.78M | xb 16.78M | Lnv 0.52M | mfl 32K
  short* qh  = (short*)d_ws;
  short* kh  = qh + (NB * NH * SQ * HD);
  short* vT  = kh + (NB * NH * SQ * HD);
  short* xb  = vT + (NB * NH * SQ * HD);
  float* Lnv = (float*)(xb + (NB * SQ * HIDN));
  float* mfl = Lnv + (NB * NH * SQ);

  k_maskprep<<<dim3(1), dim3(256), 0, stream>>>(mraw, mfl);
  k_proj_qkv<<<dim3(HIDN / 64, (NB * SQ) / 64, 3), dim3(256), 0, stream>>>(
      query, Wq, bq, Wk, bk, Wv, bv, qh, kh, vT);
  k_sumexp_m<<<dim3(SQ / 256, NB * NH), dim3(256), 0, stream>>>(qh, kh, mfl, Lnv);
  k_attnv<<<dim3(SQ / 256, NB * NH), dim3(256), 0, stream>>>(qh, kh, vT, mfl, Lnv, xb);
  k_proj_out<<<dim3(HIDN / 64, (NB * SQ) / 64), dim3(256), 0, stream>>>(
      xb, Wo, bo, (float*)d_out);
}

// Round 10
// 355.587 us; speedup vs baseline: 9.8334x; 1.1540x over previous
//
#include <hip/hip_runtime.h>

#define SQ   2048
#define HIDN 1024
#define NB   4
#define NH   16
#define HD   64

typedef __attribute__((ext_vector_type(8))) short short8;
typedef __attribute__((ext_vector_type(4))) short short4v;
typedef __attribute__((ext_vector_type(4))) float f32x4;

__device__ __forceinline__ short f2bf(float f) {
  union { float f; unsigned u; } x; x.f = f;
  unsigned r = (x.u + 0x7fffu + ((x.u >> 16) & 1u)) >> 16;
  return (short)r;
}

#define MFMA(a, b, c) __builtin_amdgcn_mfma_f32_16x16x32_bf16((a), (b), (c), 0, 0, 0)

__device__ __forceinline__ void gload16(const void* g, void* l) {
  __builtin_amdgcn_global_load_lds(
      (const __attribute__((address_space(1))) unsigned*)g,
      (__attribute__((address_space(3))) unsigned*)l, 16, 0, 0);
}

// ---------------------------------------------------------------------------
// K0: normalize mask to fp32 (auto-detect int32 / byte-bool / fp32). Verified.
// ---------------------------------------------------------------------------
__global__ __launch_bounds__(256) void k_maskprep(const unsigned* __restrict__ mraw,
                                                  float* __restrict__ m) {
  __shared__ unsigned red[256];
  const int tid = threadIdx.x;
  unsigned w_or = 0;
  for (int i = tid; i < 2048; i += 256) w_or |= mraw[i];
  red[tid] = w_or;
  __syncthreads();
  for (int s = 128; s > 0; s >>= 1) {
    if (tid < s) red[tid] |= red[tid + s];
    __syncthreads();
  }
  const unsigned allw = red[0];
  int mode;
  if ((allw & 0xFFFFFFFEu) == 0) mode = 0;
  else if ((allw & 0xFEFEFEFEu) == 0) mode = 1;
  else mode = 2;
  const unsigned char* mb = (const unsigned char*)mraw;
  const float* mf = (const float*)mraw;
  const int* mi = (const int*)mraw;
  for (int i = tid; i < NB * SQ; i += 256) {
    float v;
    if (mode == 0)      v = mi[i] ? 1.0f : 0.0f;
    else if (mode == 1) v = mb[i] ? 1.0f : 0.0f;
    else                v = (mf[i] != 0.0f) ? 1.0f : 0.0f;
    m[i] = v;
  }
}

// ---------------------------------------------------------------------------
// K0b: fp32 -> bf16 pre-convert. y=0: query -> qbf; y=1..3: Wq/Wk/Wv -> wbf.
// ---------------------------------------------------------------------------
__global__ __launch_bounds__(256) void k_cvt(
    const float* __restrict__ query, const float* __restrict__ Wq,
    const float* __restrict__ Wk, const float* __restrict__ Wv,
    short* __restrict__ qbf, short* __restrict__ wbf)
{
  const int yy = blockIdx.y;
  const float* __restrict__ src = (yy == 0) ? query : (yy == 1) ? Wq : (yy == 2) ? Wk : Wv;
  short* __restrict__ dst = (yy == 0) ? qbf : wbf + (yy - 1) * (HIDN * HIDN);
  const int n = (yy == 0) ? (NB * SQ * HIDN) : (HIDN * HIDN);
  const int i = (blockIdx.x * 256 + threadIdx.x) * 4;
  if (i >= n) return;
  const f32x4 v = *(const f32x4*)(src + i);
  short4v s;
#pragma unroll
  for (int e = 0; e < 4; ++e) s[e] = f2bf(v[e]);
  *(short4v*)(dst + i) = s;
}

// ---------------------------------------------------------------------------
// K1 v2: fused QKV projection GEMM, bf16 inputs.
// M=8192 (b*s), N=3072 (z|col: z = nt>>3 block-uniform), K=1024.
// 128x128 tile, BK=64, 4 waves (2x2, each 64x64 = 4x4 16x16 frags).
// global_load_lds(16B) staging, XOR-swizzle: linear LDS dest, pre-swizzled
// global source chunk c^(r&7), read at r*128 + ((kk*4+lg)^(r&7))*16.
// Epilogue: z=0 q*0.125 -> qh[b,h,s,d]; z=1 k -> kh; z=2 v -> vT[b,h,d,s].
// ---------------------------------------------------------------------------
__global__ __launch_bounds__(256) void k_proj_qkv2(
    const short* __restrict__ qbf, const short* __restrict__ wbf,
    const float* __restrict__ bq, const float* __restrict__ bkb,
    const float* __restrict__ bv,
    short* __restrict__ qh, short* __restrict__ kh, short* __restrict__ vT)
{
  __shared__ short a_s[128 * 64];
  __shared__ short b_s[128 * 64];
  const int nt = blockIdx.x, mt = blockIdx.y;
  const int tid = threadIdx.x;
  const int w = tid >> 6, lane = tid & 63;
  const int wr = w >> 1, wc = w & 1;
  const int lg = lane >> 4, lr = lane & 15;

  const int z = nt >> 3;   // block-uniform
  const float* __restrict__ bias = (z == 0) ? bq : (z == 1) ? bkb : bv;

  // staging descriptors: id = p*256 + tid covers 1024 chunks of 16B (128 rows x 8)
  int srow[4], scs[4], sbase[4];
#pragma unroll
  for (int p = 0; p < 4; ++p) {
    const int id = p * 256 + tid;
    const int r = id >> 3, c = id & 7;
    srow[p] = r;
    scs[p] = c ^ (r & 7);
    sbase[p] = (p * 256 + w * 64) * 8;   // wave-uniform LDS short-offset
  }

  f32x4 acc[4][4] = {};

  for (int k0 = 0; k0 < HIDN; k0 += 64) {
#pragma unroll
    for (int p = 0; p < 4; ++p) {
      const short* ga = qbf + (size_t)(mt * 128 + srow[p]) * HIDN + k0 + scs[p] * 8;
      const short* gb = wbf + (size_t)(nt * 128 + srow[p]) * HIDN + k0 + scs[p] * 8;
      gload16(ga, a_s + sbase[p]);
      gload16(gb, b_s + sbase[p]);
    }
    __syncthreads();   // drains vmcnt -> LDS tiles ready
#pragma unroll
    for (int kk = 0; kk < 2; ++kk) {
      short8 af[4], bfv[4];
#pragma unroll
      for (int mi = 0; mi < 4; ++mi) {
        const int r = wr * 64 + mi * 16 + lr;
        const int phys = (kk * 4 + lg) ^ (r & 7);
        af[mi] = *(const short8*)((const char*)a_s + r * 128 + phys * 16);
      }
#pragma unroll
      for (int ni = 0; ni < 4; ++ni) {
        const int r = wc * 64 + ni * 16 + lr;
        const int phys = (kk * 4 + lg) ^ (r & 7);
        bfv[ni] = *(const short8*)((const char*)b_s + r * 128 + phys * 16);
      }
#pragma unroll
      for (int mi = 0; mi < 4; ++mi)
#pragma unroll
        for (int ni = 0; ni < 4; ++ni)
          acc[mi][ni] = MFMA(af[mi], bfv[ni], acc[mi][ni]);
    }
    __syncthreads();   // all reads done before restage
  }

#pragma unroll
  for (int mi = 0; mi < 4; ++mi)
#pragma unroll
    for (int ni = 0; ni < 4; ++ni)
#pragma unroll
      for (int r = 0; r < 4; ++r) {
        const int row = mt * 128 + wr * 64 + mi * 16 + lg * 4 + r;  // [0,8192)
        const int colz = (nt & 7) * 128 + wc * 64 + ni * 16 + lr;   // [0,1024)
        const float v = acc[mi][ni][r] + bias[colz];
        const int bi = row >> 11, s = row & (SQ - 1);
        const int h = colz >> 6, d = colz & (HD - 1);
        if (z == 0) {
          qh[(((bi * NH + h) * SQ + s) * HD) + d] = f2bf(v * 0.125f);
        } else if (z == 1) {
          kh[(((bi * NH + h) * SQ + s) * HD) + d] = f2bf(v);
        } else {
          vT[(((bi * NH + h) * HD + d) * SQ) + s] = f2bf(v);
        }
      }
}

// ---------------------------------------------------------------------------
// K2: per-column softmax denominators (round-9 version, verified, unchanged).
// ---------------------------------------------------------------------------
__global__ __launch_bounds__(256) void k_sumexp_m(
    const short* __restrict__ qh, const short* __restrict__ kh,
    const float* __restrict__ mfl, float* __restrict__ Lnv)
{
  __shared__ float m_s[SQ];
  __shared__ short q_s[2][64][72];
  const int bh = blockIdx.y, b = bh >> 4;
  const int jt = blockIdx.x;
  const int tid = threadIdx.x, w = tid >> 6, lane = tid & 63;
  const int lg = lane >> 4, lr = lane & 15;
  for (int i = tid; i < SQ; i += 256) m_s[i] = mfl[b * SQ + i];

  const int base = bh * SQ * HD;
  const int jbase = jt * 256 + w * 64;

  short8 bk[4][2];
#pragma unroll
  for (int jf = 0; jf < 4; ++jf) {
    const int j = jbase + jf * 16 + lr;
    bk[jf][0] = *(const short8*)(kh + base + j * HD + lg * 8);
    bk[jf][1] = *(const short8*)(kh + base + j * HD + 32 + lg * 8);
  }

  const int srow = tid >> 3, scc = (tid & 7) * 8;
  {
    const short8 s0 = *(const short8*)(qh + base + srow * HD + scc);
    const short8 s1 = *(const short8*)(qh + base + (32 + srow) * HD + scc);
    *(short8*)&q_s[0][srow][scc] = s0;
    *(short8*)&q_s[0][32 + srow][scc] = s1;
  }
  __syncthreads();

  float mj[4];
#pragma unroll
  for (int jf = 0; jf < 4; ++jf) mj[jf] = m_s[jbase + jf * 16 + lr];

  f32x4 Lacc[4] = {};
  for (int t = 0; t < 32; ++t) {
    const int cur = t & 1;
    short8 n0, n1;
    if (t < 31) {
      const int ibn = (t + 1) * 64;
      n0 = *(const short8*)(qh + base + (ibn + srow) * HD + scc);
      n1 = *(const short8*)(qh + base + (ibn + 32 + srow) * HD + scc);
    }
    const int ib = t * 64;
#pragma unroll
    for (int s = 0; s < 4; ++s) {
      const short8 a0 = *(const short8*)&q_s[cur][s * 16 + lr][lg * 8];
      const short8 a1 = *(const short8*)&q_s[cur][s * 16 + lr][32 + lg * 8];
      float mrow[4];
#pragma unroll
      for (int r = 0; r < 4; ++r) mrow[r] = m_s[ib + s * 16 + lg * 4 + r];
#pragma unroll
      for (int jf = 0; jf < 4; ++jf) {
        f32x4 e = {};
        e = MFMA(a0, bk[jf][0], e);
        e = MFMA(a1, bk[jf][1], e);
#pragma unroll
        for (int r = 0; r < 4; ++r)
          Lacc[jf][r] += __expf(e[r] * (mrow[r] * mj[jf]));
      }
    }
    if (t < 31) {
      __syncthreads();
      *(short8*)&q_s[cur ^ 1][srow][scc] = n0;
      *(short8*)&q_s[cur ^ 1][32 + srow][scc] = n1;
      __syncthreads();
    }
  }

#pragma unroll
  for (int jf = 0; jf < 4; ++jf) {
    float L = Lacc[jf][0] + Lacc[jf][1] + Lacc[jf][2] + Lacc[jf][3];
    L += __shfl_xor(L, 16, 64);
    L += __shfl_xor(L, 32, 64);
    if (lg == 0) Lnv[bh * SQ + jbase + jf * 16 + lr] = 1.0f / L;
  }
}

// ---------------------------------------------------------------------------
// K3: attention-weighted V (round-8 ILP version, verified, unchanged).
// ---------------------------------------------------------------------------
__global__ __launch_bounds__(256) void k_attnv(
    const short* __restrict__ qh, const short* __restrict__ kh,
    const short* __restrict__ vT,
    const float* __restrict__ mfl, const float* __restrict__ Lnv,
    short* __restrict__ xo)
{
  __shared__ float m_s[SQ];
  __shared__ float L_s[SQ];
  __shared__ short p_s[4][4][16][40];
  const int bh = blockIdx.y, b = bh >> 4, h = bh & (NH - 1);
  const int it = blockIdx.x;
  const int tid = threadIdx.x, w = tid >> 6, lane = tid & 63;
  const int lg = lane >> 4, lr = lane & 15;
  for (int i = tid; i < SQ; i += 256) {
    m_s[i] = mfl[b * SQ + i];
    L_s[i] = Lnv[bh * SQ + i];
  }
  __syncthreads();

  const int base = bh * SQ * HD;
  const int i0 = it * 256 + w * 64;

  short8 aq[4][2];
  float mi[4][4];
#pragma unroll
  for (int fi = 0; fi < 4; ++fi) {
    aq[fi][0] = *(const short8*)(qh + base + (i0 + fi * 16 + lr) * HD + lg * 8);
    aq[fi][1] = *(const short8*)(qh + base + (i0 + fi * 16 + lr) * HD + 32 + lg * 8);
#pragma unroll
    for (int r = 0; r < 4; ++r) mi[fi][r] = m_s[i0 + fi * 16 + lg * 4 + r];
  }

  f32x4 accx[4][4] = {};
  for (int jb = 0; jb < SQ; jb += 32) {
    short8 bk[2][2];
#pragma unroll
    for (int jj = 0; jj < 2; ++jj) {
      const int j = jb + jj * 16 + lr;
      bk[jj][0] = *(const short8*)(kh + base + j * HD + lg * 8);
      bk[jj][1] = *(const short8*)(kh + base + j * HD + 32 + lg * 8);
    }
    short8 bv[4];
#pragma unroll
    for (int nd = 0; nd < 4; ++nd)
      bv[nd] = *(const short8*)(vT + base + (nd * 16 + lr) * SQ + jb + lg * 8);

#pragma unroll
    for (int fi = 0; fi < 4; ++fi) {
#pragma unroll
      for (int jj = 0; jj < 2; ++jj) {
        f32x4 e = {};
        e = MFMA(aq[fi][0], bk[jj][0], e);
        e = MFMA(aq[fi][1], bk[jj][1], e);
        const float mjv = m_s[jb + jj * 16 + lr];
        const float Ljv = L_s[jb + jj * 16 + lr];
#pragma unroll
        for (int r = 0; r < 4; ++r) {
          const float p = __expf(e[r] * (mi[fi][r] * mjv)) * Ljv;
          p_s[w][fi][lg * 4 + r][jj * 16 + lr] = f2bf(p);
        }
      }
    }
#pragma unroll
    for (int fi = 0; fi < 4; ++fi) {
      const short8 pa = *(const short8*)&p_s[w][fi][lr][lg * 8];
#pragma unroll
      for (int nd = 0; nd < 4; ++nd)
        accx[fi][nd] = MFMA(pa, bv[nd], accx[fi][nd]);
    }
  }

#pragma unroll
  for (int fi = 0; fi < 4; ++fi)
#pragma unroll
    for (int nd = 0; nd < 4; ++nd)
#pragma unroll
      for (int r = 0; r < 4; ++r) {
        const int i = i0 + fi * 16 + lg * 4 + r, d = nd * 16 + lr;
        xo[(b * SQ + i) * HIDN + h * HD + d] = f2bf(accx[fi][nd][r]);
      }
}

// ---------------------------------------------------------------------------
// K4: output projection via MFMA (verified, unchanged). FP32 out.
// ---------------------------------------------------------------------------
__global__ __launch_bounds__(256) void k_proj_out(
    const short* __restrict__ x,
    const float* __restrict__ Wo, const float* __restrict__ bo,
    float* __restrict__ out)
{
  __shared__ short a_s[64][48];
  __shared__ short b_s[64][48];
  const int nt = blockIdx.x, mt = blockIdx.y;
  const int tid = threadIdx.x;
  const int w = tid >> 6, lane = tid & 63;
  const int wr = w >> 1, wc = w & 1;
  const int lg = lane >> 4, lr = lane & 15;
  const int srow = tid >> 2, scol = (tid & 3) * 8;

  const short* aptr = x + (mt * 64 + srow) * HIDN + scol;
  const float* bptr = Wo + (nt * 64 + srow) * HIDN + scol;

  f32x4 acc[2][2] = {};

  for (int k0 = 0; k0 < HIDN; k0 += 32) {
    const short8 av = *(const short8*)(aptr + k0);
    f32x4 b0 = *(const f32x4*)(bptr + k0);
    f32x4 b1 = *(const f32x4*)(bptr + k0 + 4);
    short8 wv8;
#pragma unroll
    for (int e = 0; e < 4; ++e) { wv8[e] = f2bf(b0[e]); wv8[e + 4] = f2bf(b1[e]); }
    *(short8*)&a_s[srow][scol] = av;
    *(short8*)&b_s[srow][scol] = wv8;
    __syncthreads();
    short8 af[2], bfb[2];
#pragma unroll
    for (int mi = 0; mi < 2; ++mi)
      af[mi] = *(const short8*)&a_s[wr * 32 + mi * 16 + lr][lg * 8];
#pragma unroll
    for (int ni = 0; ni < 2; ++ni)
      bfb[ni] = *(const short8*)&b_s[wc * 32 + ni * 16 + lr][lg * 8];
#pragma unroll
    for (int mi = 0; mi < 2; ++mi)
#pragma unroll
      for (int ni = 0; ni < 2; ++ni)
        acc[mi][ni] = MFMA(af[mi], bfb[ni], acc[mi][ni]);
    __syncthreads();
  }

#pragma unroll
  for (int mi = 0; mi < 2; ++mi)
#pragma unroll
    for (int ni = 0; ni < 2; ++ni)
#pragma unroll
      for (int r = 0; r < 4; ++r) {
        const int row = mt * 64 + wr * 32 + mi * 16 + lg * 4 + r;
        const int col = nt * 64 + wc * 32 + ni * 16 + lr;
        out[row * HIDN + col] = acc[mi][ni][r] + bo[col];
      }
}

// ---------------------------------------------------------------------------
extern "C" void kernel_launch(void* const* d_in, const int* in_sizes, int n_in,
                              void* d_out, int out_size, void* d_ws, size_t ws_size,
                              hipStream_t stream) {
  const float* query = (const float*)d_in[0];
  const unsigned* mraw = (const unsigned*)d_in[1];
  const float* Wq = (const float*)d_in[2];
  const float* bq = (const float*)d_in[3];
  const float* Wk = (const float*)d_in[4];
  const float* bk = (const float*)d_in[5];
  const float* Wv = (const float*)d_in[6];
  const float* bv = (const float*)d_in[7];
  const float* Wo = (const float*)d_in[8];
  const float* bo = (const float*)d_in[9];

  // ws (shorts): qh 16.78M | kh 16.78M | vT 16.78M | xb 16.78M | Lnv 0.52M | mfl 32K
  short* qh  = (short*)d_ws;
  short* kh  = qh + (NB * NH * SQ * HD);
  short* vT  = kh + (NB * NH * SQ * HD);
  short* xb  = vT + (NB * NH * SQ * HD);
  float* Lnv = (float*)(xb + (NB * SQ * HIDN));
  float* mfl = Lnv + (NB * NH * SQ);

  // bf16 staging scratch parked in d_out (33.5 MB fp32): qbf 16.8M + wbf 6.3M
  // = 23.1 MB; dead before k_proj_out overwrites d_out with the real output.
  short* qbf = (short*)d_out;
  short* wbf = qbf + (NB * SQ * HIDN);

  k_maskprep<<<dim3(1), dim3(256), 0, stream>>>(mraw, mfl);
  k_cvt<<<dim3((NB * SQ * HIDN) / 1024, 4), dim3(256), 0, stream>>>(
      query, Wq, Wk, Wv, qbf, wbf);
  k_proj_qkv2<<<dim3(24, 64), dim3(256), 0, stream>>>(
      qbf, wbf, bq, bk, bv, qh, kh, vT);
  k_sumexp_m<<<dim3(SQ / 256, NB * NH), dim3(256), 0, stream>>>(qh, kh, mfl, Lnv);
  k_attnv<<<dim3(SQ / 256, NB * NH), dim3(256), 0, stream>>>(qh, kh, vT, mfl, Lnv, xb);
  k_proj_out<<<dim3(HIDN / 64, (NB * SQ) / 64), dim3(256), 0, stream>>>(
      xb, Wo, bo, (float*)d_out);
}